// Round 5
// baseline (204.729 us; speedup 1.0000x reference)
//
#include <hip/hip_runtime.h>

#define SEQ 2048
#define NH 16
#define HD 64
#define DMODEL 1024

__device__ __forceinline__ unsigned int f2bf(float f) {
  // fp32 -> bf16 bits, round-to-nearest-even (finite inputs only)
  unsigned int u = __float_as_uint(f);
  return ((u + 0x7fffu + ((u >> 16) & 1u)) >> 16) & 0xffffu;
}

// packed fp32x2 -> bf16x2 (RNE via __bf16 cvt)
__device__ __forceinline__ unsigned int pk2bf(float a, float b) {
  unsigned short ua = __builtin_bit_cast(unsigned short, (__bf16)a);
  unsigned short ub = __builtin_bit_cast(unsigned short, (__bf16)b);
  return (unsigned int)ua | ((unsigned int)ub << 16);
}

typedef __bf16 bf16x8 __attribute__((ext_vector_type(8)));
typedef float f32x4 __attribute__((ext_vector_type(4)));
typedef unsigned int uix4 __attribute__((ext_vector_type(4)));
typedef unsigned int uix2 __attribute__((ext_vector_type(2)));

// async global->LDS, 16B per lane; LDS dest = wave-uniform base + lane*16
__device__ __forceinline__ void gl2lds16(const unsigned short* g, unsigned short* l) {
  __builtin_amdgcn_global_load_lds(
      (const __attribute__((address_space(1))) unsigned int*)g,
      (__attribute__((address_space(3))) unsigned int*)l, 16, 0, 0);
}

// one launch casts x + all four weight matrices to bf16
__global__ __launch_bounds__(256) void cast_all_kernel(
    const float* __restrict__ x, const float* __restrict__ wq,
    const float* __restrict__ wk, const float* __restrict__ wv,
    const float* __restrict__ wo,
    unsigned short* __restrict__ xb, unsigned short* __restrict__ wqb,
    unsigned short* __restrict__ wkb, unsigned short* __restrict__ wvb,
    unsigned short* __restrict__ wob) {
  int idx = blockIdx.x * 256 + threadIdx.x;
  if (idx >= 1048576) return;
  const float* src;
  unsigned short* dst;
  int off;
  if (idx < 524288) {
    src = x; dst = xb; off = idx;
  } else {
    int t = idx - 524288;
    int w = t >> 17;
    off = t & 131071;
    src = (w == 0) ? wq : (w == 1) ? wk : (w == 2) ? wv : wo;
    dst = (w == 0) ? wqb : (w == 1) ? wkb : (w == 2) ? wvb : wob;
  }
  const float4* p = reinterpret_cast<const float4*>(src) + (size_t)off * 2;
  float4 a = p[0], b = p[1];
  uint4 o;
  o.x = f2bf(a.x) | (f2bf(a.y) << 16);
  o.y = f2bf(a.z) | (f2bf(a.w) << 16);
  o.z = f2bf(b.x) | (f2bf(b.y) << 16);
  o.w = f2bf(b.z) | (f2bf(b.w) << 16);
  reinterpret_cast<uint4*>(dst)[off] = o;
}

// TM x 128-tile GEMM, BK=64, global_load_lds staging, XOR-swizzled LDS chunks.
// Double-buffered LDS, ONE barrier per K-step.
// MODE 0: fused QKV epilogue (cols 0..1023 Q *qscale, 1024..2047 K, 2048..3071 V^T).
// MODE 1: fp32 C[M][1024] + bias0 (out projection).
template <int MODE, int TM>
__global__ __launch_bounds__(256) void gemm128(
    const unsigned short* __restrict__ A, const unsigned short* __restrict__ B,
    const float* __restrict__ bias0, const float* __restrict__ bias1,
    const float* __restrict__ bias2, float* __restrict__ Cf,
    unsigned short* __restrict__ Qo, unsigned short* __restrict__ Ko,
    unsigned short* __restrict__ Vto, int Kdim) {
  constexpr int MT = TM / 32;  // acc rows (16-row frags) per wave
  __shared__ __align__(16) unsigned short As[2][TM * 64];
  __shared__ __align__(16) unsigned short Bs[2][128 * 64];
  const int tid = threadIdx.x;
  const int wave = tid >> 6, lane = tid & 63;
  const int wm = wave >> 1, wn = wave & 1;  // 2x2 waves
  const int fr = lane & 15, quad = lane >> 4;
  const int fx = fr & 7;  // swizzle key for fragment reads
  const int n0 = blockIdx.x * 128, m0 = blockIdx.y * TM;

  // staging: lane -> (row = lane>>3, swizzled chunk = (lane&7) ^ ((lane>>3)&7))
  const int srowg = lane >> 3;
  const int schunk = (lane & 7) ^ (srowg & 7);
  const unsigned short* Abase =
      A + (size_t)(m0 + wave * (TM / 4) + srowg) * Kdim + schunk * 8;
  const unsigned short* Bbase =
      B + (size_t)(n0 + wave * 32 + srowg) * Kdim + schunk * 8;
  const int awoff = (wave * (TM / 4)) * 64;
  const int bwoff = (wave * 32) * 64;

  f32x4 acc[MT][4];
#pragma unroll
  for (int mt = 0; mt < MT; ++mt)
#pragma unroll
    for (int nt = 0; nt < 4; ++nt) acc[mt][nt] = f32x4{0.f, 0.f, 0.f, 0.f};

  // prologue: stage K-tile 0 into buffer 0
#pragma unroll
  for (int t = 0; t < TM / 32; ++t)
    gl2lds16(Abase + (size_t)(t * 8) * Kdim, As[0] + awoff + t * 8 * 64);
#pragma unroll
  for (int t = 0; t < 4; ++t)
    gl2lds16(Bbase + (size_t)(t * 8) * Kdim, Bs[0] + bwoff + t * 8 * 64);

  const int nk = Kdim >> 6;
  for (int kk = 0; kk < nk; ++kk) {
    __syncthreads();   // drains DMA[kk] (vmcnt) + guards buffer reuse
    if (kk + 1 < nk) { // prefetch next K-tile into the other buffer
      const int k0n = (kk + 1) * 64;
      unsigned short* An = As[(kk + 1) & 1] + awoff;
      unsigned short* Bn = Bs[(kk + 1) & 1] + bwoff;
#pragma unroll
      for (int t = 0; t < TM / 32; ++t)
        gl2lds16(Abase + (size_t)(t * 8) * Kdim + k0n, An + t * 8 * 64);
#pragma unroll
      for (int t = 0; t < 4; ++t)
        gl2lds16(Bbase + (size_t)(t * 8) * Kdim + k0n, Bn + t * 8 * 64);
    }
    const unsigned short* Acur = As[kk & 1];
    const unsigned short* Bcur = Bs[kk & 1];
#pragma unroll
    for (int ks = 0; ks < 2; ++ks) {
      bf16x8 af[MT], bfv[4];
#pragma unroll
      for (int mt = 0; mt < MT; ++mt)
        af[mt] = *reinterpret_cast<const bf16x8*>(
            Acur + (wm * (TM / 2) + mt * 16 + fr) * 64 + ((ks * 4 + quad) ^ fx) * 8);
#pragma unroll
      for (int nt = 0; nt < 4; ++nt)
        bfv[nt] = *reinterpret_cast<const bf16x8*>(
            Bcur + (wn * 64 + nt * 16 + fr) * 64 + ((ks * 4 + quad) ^ fx) * 8);
#pragma unroll
      for (int mt = 0; mt < MT; ++mt)
#pragma unroll
        for (int nt = 0; nt < 4; ++nt)
          acc[mt][nt] = __builtin_amdgcn_mfma_f32_16x16x32_bf16(
              af[mt], bfv[nt], acc[mt][nt], 0, 0, 0);
    }
  }

  // epilogue. C/D: col = lane&15, row = quad*4+reg (m89/m91-verified).
  if (MODE == 0) {
    const int seg = n0 >> 10;  // uniform per block
    const float* bp = (seg == 0) ? bias0 : (seg == 1) ? bias1 : bias2;
    // Q pre-scaled by (1/sqrt(64)) * log2(e): attention works in exp2 domain
    const float scale = (seg == 0) ? 0.1803368809f : 1.0f;
    unsigned short* QK = (seg == 0) ? Qo : Ko;
#pragma unroll
    for (int nt = 0; nt < 4; ++nt) {
      const int c = (n0 + wn * 64 + nt * 16 + fr) & 1023;
      const int h = c >> 6, d = c & 63;
      const float bs = bp[c];
#pragma unroll
      for (int mt = 0; mt < MT; ++mt) {
        const int mbase = m0 + wm * (TM / 2) + mt * 16 + quad * 4;
        const int b = mbase >> 11, s0 = mbase & 2047;
        if (seg < 2) {
          unsigned short* dst = QK + (((size_t)(b * NH + h)) * SEQ + s0) * HD + d;
#pragma unroll
          for (int r = 0; r < 4; ++r)
            dst[(size_t)r * HD] = (unsigned short)f2bf((acc[mt][nt][r] + bs) * scale);
        } else {  // V^T: rows contiguous in s -> 8B store
          uint2 pk;
          pk.x = pk2bf(acc[mt][nt][0] + bs, acc[mt][nt][1] + bs);
          pk.y = pk2bf(acc[mt][nt][2] + bs, acc[mt][nt][3] + bs);
          *reinterpret_cast<uint2*>(
              Vto + (((size_t)(b * NH + h)) * HD + d) * SEQ + s0) = pk;
        }
      }
    }
  } else {
#pragma unroll
    for (int nt = 0; nt < 4; ++nt) {
      const int cg = n0 + wn * 64 + nt * 16 + fr;
      const float bs = bias0[cg];
#pragma unroll
      for (int mt = 0; mt < MT; ++mt) {
        const int mbase = m0 + wm * (TM / 2) + mt * 16 + quad * 4;
#pragma unroll
        for (int r = 0; r < 4; ++r)
          Cf[(size_t)(mbase + r) * DMODEL + cg] = acc[mt][nt][r] + bs;
      }
    }
  }
}

// MFMA flash attention, exp2 domain. Single 64-row i-tile per block, grid 1024.
// ROUND 5: 2-wave blocks (128 threads); each wave owns 32 i-rows (2 i-tiles).
// Rationale: with 4 waves, all waves read IDENTICAL K/V fragments from LDS
// (each computes all 64 j for its own 16 i) -> every K/V byte crossed the LDS
// pipe 4x (~43% LDS-pipe busy at 12 cyc/b128). Now K/V frags are read once per
// wave and reused for both i-tiles in registers: per-block LDS reads halved,
// per-wave ILP doubled (two independent QK->softmax->PV chains), LDS still
// 32 KB -> 5 blocks/CU resident.
// Round-2 trick: K-tile ROWS are permuted at DMA time with pi(m) = m5*32 +
// m[3:2]*8 + m4*4 + m[1:0], so each lane's own S^T outputs ARE its PV
// B-fragment -> P never touches LDS.
// Round-3 trick (STALE-MAX): P uses the previous pass's running max; the max
// reduction runs in the PV shadow; rare threshold-8 rescale applied post-PV.
__global__ __launch_bounds__(128, 3) void attn_mfma_kernel(
    const unsigned short* __restrict__ Qg, const unsigned short* __restrict__ Kg,
    const unsigned short* __restrict__ Vtg, const int* __restrict__ mask,
    unsigned short* __restrict__ concat) {
  const int w = blockIdx.x >> 8;        // phase 0..3
  const int c = blockIdx.x & 255;
  const int gg = c >> 5;                // 0..7
  const int bh = c & 31;
  const int ib = (w == 0) ? (31 - gg) : (w == 1) ? gg : (w == 2) ? (23 - gg) : (8 + gg);
  const int b = bh >> 4, h = bh & 15;
  const int tid = threadIdx.x;
  const int wave = tid >> 6, lane = tid & 63;
  const int quad = lane >> 4, fr = lane & 15;
  const int fx = fr & 7;

  __shared__ __align__(16) unsigned short Ks[2][64 * 64];   // swizzled, pitch 64, pi-permuted rows
  __shared__ __align__(16) unsigned short Vts[2][64 * 64];  // swizzled, pitch 64

  const unsigned short* Qb = Qg + ((size_t)bh * SEQ) * HD;
  const unsigned short* Kb = Kg + ((size_t)bh * SEQ) * HD;
  const unsigned short* Vtb = Vtg + ((size_t)bh * HD) * SEQ;
  const int* maskb = mask + b * SEQ;

  // pad-mask tile bitmap via wave ballot: lane covers ints [lane*32, lane*32+32)
  // -> tile jc covered by ballot bits {2jc, 2jc+1}  (computed per wave)
  bool badl = false;
  {
    const int4* mp4 = reinterpret_cast<const int4*>(maskb);
#pragma unroll
    for (int u = 0; u < 8; ++u) {
      int4 v = mp4[lane * 8 + u];
      badl |= !(v.x && v.y && v.z && v.w);
    }
  }
  const unsigned long long bm = __ballot(badl);

  // this wave's two Q rows (softmax owners): ir[it] = ib*64 + wave*32 + it*16 + fr
  int ir[2], padi[2];
  bf16x8 q[2][2];
#pragma unroll
  for (int it = 0; it < 2; ++it) {
    ir[it] = ib * 64 + wave * 32 + it * 16 + fr;
    q[it][0] = *reinterpret_cast<const bf16x8*>(Qb + (size_t)ir[it] * HD + quad * 8);
    q[it][1] = *reinterpret_cast<const bf16x8*>(Qb + (size_t)ir[it] * HD + quad * 8 + 32);
    padi[it] = maskb[ir[it]];
  }

  f32x4 o[2][4];
#pragma unroll
  for (int it = 0; it < 2; ++it)
#pragma unroll
    for (int vt = 0; vt < 4; ++vt) o[it][vt] = f32x4{0.f, 0.f, 0.f, 0.f};
  float mr[2] = {-1e20f, -1e20f};  // seeded from pass 0's real max
  float lq[2] = {0.f, 0.f};        // per-quad partial row-sums

  // staging: wave stages LDS rows [wave*32, wave*32+32) of K and V^T tiles,
  // 4 DMA calls each (t=0..3, 8 rows per call).
  // lane -> (sr = lane>>3 within the 8-row group, chunk = (lane&7)^(sr&7)).
  // K rows pi-permuted: LDS row m = wave*32 + t*8 + sr -> global row j0+pi(m):
  //   m5=wave, m4=t>>1, m3=t&1, m[2:0]=sr  ->
  //   pi = wave*32 + (t&1)*16 + (sr>>2)*8 + (t>>1)*4 + (sr&3).
  const int sr = lane >> 3;
  const int sch = (lane & 7) ^ (sr & 7);
  const unsigned short* Kcol = Kb + sch * 8;
  const unsigned short* Vsrc = Vtb + (size_t)(wave * 32 + sr) * SEQ + sch * 8;
  const int cA0 = (quad ^ fx) * 8;        // frag chunk for k in [0,32)
  const int cA1 = ((quad + 4) ^ fx) * 8;  // frag chunk for k in [32,64)

  // pre-issue DMA for jc=0 into buffer 0
#pragma unroll
  for (int t = 0; t < 4; ++t) {
    const int kp = wave * 32 + ((t & 1) << 4) + ((sr >> 2) << 3) + ((t >> 1) << 2) + (sr & 3);
    gl2lds16(Kcol + (size_t)kp * HD, Ks[0] + (wave * 32 + t * 8) * 64);
    gl2lds16(Vsrc + (size_t)(t * 8) * SEQ, Vts[0] + (wave * 32 + t * 8) * 64);
  }

  for (int jc = 0; jc <= ib; ++jc) {
    __syncthreads();  // drains DMA[jc] (vmcnt) + guards buffer reuse
    if (jc < ib) {    // prefetch next tile into the other buffer
      const int jn = (jc + 1) * 64;
      unsigned short* Ksn = Ks[(jc + 1) & 1];
      unsigned short* Vtsn = Vts[(jc + 1) & 1];
#pragma unroll
      for (int t = 0; t < 4; ++t) {
        const int kp = wave * 32 + ((t & 1) << 4) + ((sr >> 2) << 3) + ((t >> 1) << 2) + (sr & 3);
        gl2lds16(Kcol + (size_t)(jn + kp) * HD, Ksn + (wave * 32 + t * 8) * 64);
        gl2lds16(Vsrc + (size_t)(t * 8) * SEQ + jn, Vtsn + (wave * 32 + t * 8) * 64);
      }
    }
    const unsigned short* Kcur = Ks[jc & 1];
    const unsigned short* Vcur = Vts[jc & 1];
    const int j0 = jc * 64;
    const bool tb = ((bm >> (2 * jc)) & 3ull) != 0ull;

    // S^T strips: K-frags read ONCE, used for both i-tiles
    f32x4 st[2][4];
    __builtin_amdgcn_s_setprio(1);
#pragma unroll
    for (int jt = 0; jt < 4; ++jt) {
      bf16x8 ka0 = *reinterpret_cast<const bf16x8*>(&Kcur[(jt * 16 + fr) * 64 + cA0]);
      bf16x8 ka1 = *reinterpret_cast<const bf16x8*>(&Kcur[(jt * 16 + fr) * 64 + cA1]);
#pragma unroll
      for (int it = 0; it < 2; ++it) {
        st[it][jt] = f32x4{0.f, 0.f, 0.f, 0.f};
        st[it][jt] = __builtin_amdgcn_mfma_f32_16x16x32_bf16(ka0, q[it][0], st[it][jt], 0, 0, 0);
        st[it][jt] = __builtin_amdgcn_mfma_f32_16x16x32_bf16(ka1, q[it][1], st[it][jt], 0, 0, 0);
      }
    }
    __builtin_amdgcn_s_setprio(0);

    // lane (quad,fr) reg (jt,r) holds score for column j0 + pjb(jt,quad) + r,
    // pjb = (jt>>1)*32 + quad*8 + (jt&1)*4   (the pi permutation)
    if (tb) {  // rare: per-element pad-col mask (same j for both it)
      const int4* mp = reinterpret_cast<const int4*>(maskb + j0);
#pragma unroll
      for (int jt = 0; jt < 4; ++jt) {
        const int4 mv = mp[(jt >> 1) * 8 + quad * 2 + (jt & 1)];
#pragma unroll
        for (int it = 0; it < 2; ++it) {
          if (mv.x == 0) st[it][jt][0] = -1e30f;
          if (mv.y == 0) st[it][jt][1] = -1e30f;
          if (mv.z == 0) st[it][jt][2] = -1e30f;
          if (mv.w == 0) st[it][jt][3] = -1e30f;
        }
      }
    }
    if (jc == ib) {  // diagonal tile: causal mask (pi-permuted columns)
#pragma unroll
      for (int jt = 0; jt < 4; ++jt) {
        const int jb = j0 + (jt >> 1) * 32 + quad * 8 + (jt & 1) * 4;
#pragma unroll
        for (int it = 0; it < 2; ++it)
#pragma unroll
          for (int r = 0; r < 4; ++r)
            if (jb + r > ir[it]) st[it][jt][r] = -1e30f;
      }
    }

    // row max per i-tile: in-lane tree + ^16 shuffle + permlane32 swap.
    // For jc>0 this is OFF the critical path (P uses stale mr).
    float tmax[2];
#pragma unroll
    for (int it = 0; it < 2; ++it) {
      float t0 = -1e30f;
#pragma unroll
      for (int jt = 0; jt < 4; ++jt)
#pragma unroll
        for (int r = 0; r < 4; ++r) t0 = fmaxf(t0, st[it][jt][r]);
      t0 = fmaxf(t0, __shfl_xor(t0, 16));
      uix2 rr = __builtin_amdgcn_permlane32_swap(__float_as_uint(t0),
                                                 __float_as_uint(t0), false, false);
      tmax[it] = fmaxf(__uint_as_float(rr.x), __uint_as_float(rr.y));
    }
    if (jc == 0) {
      mr[0] = fmaxf(tmax[0], -1e20f);
      mr[1] = fmaxf(tmax[1], -1e20f);
    }

    // P with (stale for jc>0) mr; pack into PV B-fragments in-register
    bf16x8 pa[2][2];
#pragma unroll
    for (int it = 0; it < 2; ++it) {
      unsigned int pw[8];
#pragma unroll
      for (int jt = 0; jt < 4; ++jt) {
        float p0 = __builtin_amdgcn_exp2f(fminf(st[it][jt][0] - mr[it], 60.f));
        float p1 = __builtin_amdgcn_exp2f(fminf(st[it][jt][1] - mr[it], 60.f));
        float p2 = __builtin_amdgcn_exp2f(fminf(st[it][jt][2] - mr[it], 60.f));
        float p3 = __builtin_amdgcn_exp2f(fminf(st[it][jt][3] - mr[it], 60.f));
        lq[it] += (p0 + p1) + (p2 + p3);
        pw[2 * jt] = pk2bf(p0, p1);
        pw[2 * jt + 1] = pk2bf(p2, p3);
      }
      pa[it][0] = __builtin_bit_cast(bf16x8, uix4{pw[0], pw[1], pw[2], pw[3]});
      pa[it][1] = __builtin_bit_cast(bf16x8, uix4{pw[4], pw[5], pw[6], pw[7]});
    }

    // O^T += V^T * P^T   (V-frags read ONCE, used for both i-tiles)
    __builtin_amdgcn_s_setprio(1);
#pragma unroll
    for (int vt = 0; vt < 4; ++vt) {
      bf16x8 vb0 = *reinterpret_cast<const bf16x8*>(&Vcur[(vt * 16 + fr) * 64 + cA0]);
      bf16x8 vb1 = *reinterpret_cast<const bf16x8*>(&Vcur[(vt * 16 + fr) * 64 + cA1]);
#pragma unroll
      for (int it = 0; it < 2; ++it) {
        o[it][vt] = __builtin_amdgcn_mfma_f32_16x16x32_bf16(vb0, pa[it][0], o[it][vt], 0, 0, 0);
        o[it][vt] = __builtin_amdgcn_mfma_f32_16x16x32_bf16(vb1, pa[it][1], o[it][vt], 0, 0, 0);
      }
    }
    __builtin_amdgcn_s_setprio(0);

    // post-hoc max update (defer threshold 8, exp2 domain), applied post-PV
    if (jc > 0) {
      const bool need = (tmax[0] > mr[0] + 8.f) || (tmax[1] > mr[1] + 8.f);
      if (__ballot(need) != 0ull) {  // wave-uniform
#pragma unroll
        for (int it = 0; it < 2; ++it) {
          const float mn = fmaxf(mr[it], tmax[it]);
          const float corr = __builtin_amdgcn_exp2f(mr[it] - mn);
          mr[it] = mn;
          lq[it] *= corr;
#pragma unroll
          for (int vt = 0; vt < 4; ++vt) {
            o[it][vt][0] *= corr; o[it][vt][1] *= corr;
            o[it][vt][2] *= corr; o[it][vt][3] *= corr;
          }
        }
      }
    }
  }

  // epilogue: cross-quad l reduction, then O^T / l -> concat bf16 [b,s,h*64]
#pragma unroll
  for (int it = 0; it < 2; ++it) {
    float lr = lq[it];
    lr += __shfl_xor(lr, 16);
    lr += __shfl_xor(lr, 32);
    const float inv = (padi[it] != 0 && lr > 0.f) ? 1.f / lr : 0.f;
    unsigned short* orow = concat + ((size_t)(b * SEQ + ir[it])) * DMODEL + h * HD;
#pragma unroll
    for (int vt = 0; vt < 4; ++vt) {
      uint2 pk;
      pk.x = pk2bf(o[it][vt][0] * inv, o[it][vt][1] * inv);
      pk.y = pk2bf(o[it][vt][2] * inv, o[it][vt][3] * inv);
      *reinterpret_cast<uint2*>(orow + vt * 16 + quad * 4) = pk;
    }
  }
}

extern "C" void kernel_launch(void* const* d_in, const int* in_sizes, int n_in,
                              void* d_out, int out_size, void* d_ws, size_t ws_size,
                              hipStream_t stream) {
  (void)in_sizes; (void)n_in; (void)out_size;
  const float* x  = (const float*)d_in[0];
  const int* mask = (const int*)d_in[1];
  const float* Wq = (const float*)d_in[2];
  const float* bq = (const float*)d_in[3];
  const float* Wk = (const float*)d_in[4];
  const float* bk = (const float*)d_in[5];
  const float* Wv = (const float*)d_in[6];
  const float* bv = (const float*)d_in[7];
  const float* Wo = (const float*)d_in[8];
  const float* bo = (const float*)d_in[9];
  float* out = (float*)d_out;

  char* ws = (char*)d_ws;
  if (ws_size < (48ull << 20)) return;
  unsigned short* xb  = (unsigned short*)(ws);                 // 8 MB x bf16 [4096][1024]
  unsigned short* wqb = (unsigned short*)(ws + (8ull  << 20)); // wq|wk|wv contiguous ->
  unsigned short* wkb = (unsigned short*)(ws + (10ull << 20)); //   [3072][1024] B matrix
  unsigned short* wvb = (unsigned short*)(ws + (12ull << 20));
  unsigned short* wob = (unsigned short*)(ws + (14ull << 20));
  unsigned short* Qb  = (unsigned short*)(ws + (16ull << 20)); // 8 MB [b,h,s,64] (xscale)
  unsigned short* Kb  = (unsigned short*)(ws + (24ull << 20)); // 8 MB [b,h,s,64]
  unsigned short* Vtb = (unsigned short*)(ws + (32ull << 20)); // 8 MB [b,h,64,s]
  unsigned short* cb  = (unsigned short*)(ws + (40ull << 20)); // 8 MB concat bf16

  cast_all_kernel<<<4096, 256, 0, stream>>>(x, Wq, Wk, Wv, Wo, xb, wqb, wkb, wvb, wob);

  // fused QKV projection: B = [wq; wk; wv] = [3072][1024]
  gemm128<0, 128><<<dim3(24, 32), 256, 0, stream>>>(xb, wqb, bq, bk, bv,
                                                    nullptr, Qb, Kb, Vtb, 1024);

  attn_mfma_kernel<<<1024, 128, 0, stream>>>(Qb, Kb, Vtb, mask, cb);

  // out projection: 64-row M-tiles -> 512 blocks (2/CU)
  gemm128<1, 64><<<dim3(8, 64), 256, 0, stream>>>(cb, wob, bo, nullptr, nullptr,
                                                  out, nullptr, nullptr, nullptr, 1024);
}

// Round 6
// 197.739 us; speedup vs baseline: 1.0353x; 1.0353x over previous
//
#include <hip/hip_runtime.h>

#define SEQ 2048
#define NH 16
#define HD 64
#define DMODEL 1024

__device__ __forceinline__ unsigned int f2bf(float f) {
  // fp32 -> bf16 bits, round-to-nearest-even (finite inputs only)
  unsigned int u = __float_as_uint(f);
  return ((u + 0x7fffu + ((u >> 16) & 1u)) >> 16) & 0xffffu;
}

// packed fp32x2 -> bf16x2 (RNE via __bf16 cvt)
__device__ __forceinline__ unsigned int pk2bf(float a, float b) {
  unsigned short ua = __builtin_bit_cast(unsigned short, (__bf16)a);
  unsigned short ub = __builtin_bit_cast(unsigned short, (__bf16)b);
  return (unsigned int)ua | ((unsigned int)ub << 16);
}

typedef __bf16 bf16x8 __attribute__((ext_vector_type(8)));
typedef float f32x4 __attribute__((ext_vector_type(4)));
typedef unsigned int uix4 __attribute__((ext_vector_type(4)));
typedef unsigned int uix2 __attribute__((ext_vector_type(2)));

// async global->LDS, 16B per lane; LDS dest = wave-uniform base + lane*16
__device__ __forceinline__ void gl2lds16(const unsigned short* g, unsigned short* l) {
  __builtin_amdgcn_global_load_lds(
      (const __attribute__((address_space(1))) unsigned int*)g,
      (__attribute__((address_space(3))) unsigned int*)l, 16, 0, 0);
}

// one launch casts x + all four weight matrices to bf16
__global__ __launch_bounds__(256) void cast_all_kernel(
    const float* __restrict__ x, const float* __restrict__ wq,
    const float* __restrict__ wk, const float* __restrict__ wv,
    const float* __restrict__ wo,
    unsigned short* __restrict__ xb, unsigned short* __restrict__ wqb,
    unsigned short* __restrict__ wkb, unsigned short* __restrict__ wvb,
    unsigned short* __restrict__ wob) {
  int idx = blockIdx.x * 256 + threadIdx.x;
  if (idx >= 1048576) return;
  const float* src;
  unsigned short* dst;
  int off;
  if (idx < 524288) {
    src = x; dst = xb; off = idx;
  } else {
    int t = idx - 524288;
    int w = t >> 17;
    off = t & 131071;
    src = (w == 0) ? wq : (w == 1) ? wk : (w == 2) ? wv : wo;
    dst = (w == 0) ? wqb : (w == 1) ? wkb : (w == 2) ? wvb : wob;
  }
  const float4* p = reinterpret_cast<const float4*>(src) + (size_t)off * 2;
  float4 a = p[0], b = p[1];
  uint4 o;
  o.x = f2bf(a.x) | (f2bf(a.y) << 16);
  o.y = f2bf(a.z) | (f2bf(a.w) << 16);
  o.z = f2bf(b.x) | (f2bf(b.y) << 16);
  o.w = f2bf(b.z) | (f2bf(b.w) << 16);
  reinterpret_cast<uint4*>(dst)[off] = o;
}

// ---------------------------------------------------------------------------
// ROUND 6: 8-phase 256x256 QKV GEMM (T3+T4 schedule, plain HIP).
// 512 threads = 8 waves (wm 0..1 x wn 0..3); per-wave output 128x64.
// K=1024 = 16 K-tiles of 64; slot0 holds even tiles, slot1 odd (128 KB LDS).
// Iter j (8 phases): p0-3 compute tile 2j (slot0) + stage tile 2j+1 -> slot1
// (one half-tile per phase: A-h0, A-h1, B-h0, B-h1); p4-7 compute tile 2j+1
// (slot1) + stage tile 2j+2 -> slot0. Counted s_waitcnt vmcnt(2) ONLY at
// p0/p4 (drains the 8 loads of the tile being entered; this phase's 2 stay
// in flight) - never vmcnt(0) in the loop. Two raw s_barriers per phase
// (read/stage | MFMA split) create the wave role-split that makes setprio pay.
// Last iter over-stages a garbage tile (reads land in mapped workspace,
// never consumed) to keep the wait structure uniform.
// Swizzle: both-sides chunk-XOR (chunk ^= row&7), same scheme proven
// conflict-free in the 128^2 kernels (rule #21: pre-swizzled global source +
// swizzled LDS read, linear DMA dest).
// Epilogue: fused QKV split (Q *qscale exp2-domain, K, V^T) - index math
// copied verbatim from the proven 128^2 MODE-0 epilogue, mt extended to 8.
// ---------------------------------------------------------------------------
__global__ __launch_bounds__(512, 2) void gemm8ph_qkv(
    const unsigned short* __restrict__ A, const unsigned short* __restrict__ B,
    const float* __restrict__ bias0, const float* __restrict__ bias1,
    const float* __restrict__ bias2,
    unsigned short* __restrict__ Qo, unsigned short* __restrict__ Ko,
    unsigned short* __restrict__ Vto) {
  constexpr int KD = 1024;
  __shared__ __align__(16) unsigned short Asl[2][256 * 64];
  __shared__ __align__(16) unsigned short Bsl[2][256 * 64];
  const int tid = threadIdx.x;
  const int wave = tid >> 6, lane = tid & 63;
  const int wm = wave >> 2, wn = wave & 3;
  const int fr = lane & 15, quad = lane >> 4;
  const int fx = fr & 7;
  const int n0 = blockIdx.x * 256, m0 = blockIdx.y * 256;

  // staging: per call a wave covers 8 rows; lane -> (row = lane>>3,
  // pre-swizzled chunk = (lane&7) ^ (row&7)); 2 calls = 1 half-tile sweep pair
  const int sr = lane >> 3;
  const int sch = (lane & 7) ^ (sr & 7);
  const unsigned short* Ab = A + (size_t)(m0 + wave * 8 + sr) * KD + sch * 8;
  const unsigned short* Bb = B + (size_t)(n0 + wave * 8 + sr) * KD + sch * 8;

  f32x4 acc[8][4];
#pragma unroll
  for (int mt = 0; mt < 8; ++mt)
#pragma unroll
    for (int nt = 0; nt < 4; ++nt) acc[mt][nt] = f32x4{0.f, 0.f, 0.f, 0.f};

#define G8_STAGE_A(slot, h, k0)                                         \
  do {                                                                  \
    gl2lds16(Ab + (size_t)((h) * 128) * KD + (k0),                      \
             &Asl[slot][((h) * 128 + wave * 8) * 64]);                  \
    gl2lds16(Ab + (size_t)((h) * 128 + 64) * KD + (k0),                 \
             &Asl[slot][((h) * 128 + 64 + wave * 8) * 64]);             \
  } while (0)
#define G8_STAGE_B(slot, h, k0)                                         \
  do {                                                                  \
    gl2lds16(Bb + (size_t)((h) * 128) * KD + (k0),                      \
             &Bsl[slot][((h) * 128 + wave * 8) * 64]);                  \
    gl2lds16(Bb + (size_t)((h) * 128 + 64) * KD + (k0),                 \
             &Bsl[slot][((h) * 128 + 64 + wave * 8) * 64]);             \
  } while (0)
#define G8_READ(s, mq, nq)                                              \
  bf16x8 af[4][2], bfv[2][2];                                           \
  _Pragma("unroll") for (int f = 0; f < 4; ++f)                         \
  _Pragma("unroll") for (int ks = 0; ks < 2; ++ks)                      \
      af[f][ks] = *reinterpret_cast<const bf16x8*>(                     \
          &Asl[s][(wm * 128 + ((mq)*4 + f) * 16 + fr) * 64 +            \
                  ((ks * 4 + quad) ^ fx) * 8]);                         \
  _Pragma("unroll") for (int g = 0; g < 2; ++g)                         \
  _Pragma("unroll") for (int ks = 0; ks < 2; ++ks)                      \
      bfv[g][ks] = *reinterpret_cast<const bf16x8*>(                    \
          &Bsl[s][(wn * 64 + ((nq)*2 + g) * 16 + fr) * 64 +             \
                  ((ks * 4 + quad) ^ fx) * 8]);
#define G8_MMA(mq, nq)                                                  \
  __builtin_amdgcn_s_setprio(1);                                        \
  _Pragma("unroll") for (int ks = 0; ks < 2; ++ks)                      \
  _Pragma("unroll") for (int f = 0; f < 4; ++f)                         \
  _Pragma("unroll") for (int g = 0; g < 2; ++g)                         \
      acc[(mq)*4 + f][(nq)*2 + g] =                                     \
          __builtin_amdgcn_mfma_f32_16x16x32_bf16(                      \
              af[f][ks], bfv[g][ks], acc[(mq)*4 + f][(nq)*2 + g], 0, 0, 0); \
  __builtin_amdgcn_s_setprio(0);
#define G8_BAR asm volatile("s_barrier" ::: "memory")
#define G8_VM2 asm volatile("s_waitcnt vmcnt(2)" ::: "memory")

  // prologue: tile 0 -> slot0 (8 loads/thread-wave)
  G8_STAGE_A(0, 0, 0); G8_STAGE_A(0, 1, 0);
  G8_STAGE_B(0, 0, 0); G8_STAGE_B(0, 1, 0);

  for (int j = 0; j < 8; ++j) {
    const int kB = j * 128 + 64;   // odd tile 2j+1
    const int kC = j * 128 + 128;  // even tile 2j+2 (j=7: mapped garbage)
    {  // p0: enter slot0 (tile 2j)
      G8_STAGE_A(1, 0, kB); G8_VM2; G8_BAR;
      G8_READ(0, 0, 0) G8_MMA(0, 0) G8_BAR;
    }
    {  // p1
      G8_READ(0, 0, 1) G8_STAGE_A(1, 1, kB); G8_BAR; G8_MMA(0, 1) G8_BAR;
    }
    {  // p2
      G8_READ(0, 1, 0) G8_STAGE_B(1, 0, kB); G8_BAR; G8_MMA(1, 0) G8_BAR;
    }
    {  // p3
      G8_READ(0, 1, 1) G8_STAGE_B(1, 1, kB); G8_BAR; G8_MMA(1, 1) G8_BAR;
    }
    {  // p4: enter slot1 (tile 2j+1)
      G8_STAGE_A(0, 0, kC); G8_VM2; G8_BAR;
      G8_READ(1, 0, 0) G8_MMA(0, 0) G8_BAR;
    }
    {  // p5
      G8_READ(1, 0, 1) G8_STAGE_A(0, 1, kC); G8_BAR; G8_MMA(0, 1) G8_BAR;
    }
    {  // p6
      G8_READ(1, 1, 0) G8_STAGE_B(0, 0, kC); G8_BAR; G8_MMA(1, 0) G8_BAR;
    }
    {  // p7
      G8_READ(1, 1, 1) G8_STAGE_B(0, 1, kC); G8_BAR; G8_MMA(1, 1) G8_BAR;
    }
  }

  // fused QKV epilogue (per-block segment is uniform: 256-col tile never
  // crosses a 1024-col segment boundary). C/D: col=lane&15, row=quad*4+reg.
  const int seg = n0 >> 10;
  const float* bp = (seg == 0) ? bias0 : (seg == 1) ? bias1 : bias2;
  const float scale = (seg == 0) ? 0.1803368809f : 1.0f;  // (1/8)*log2(e)
  unsigned short* QK = (seg == 0) ? Qo : Ko;
#pragma unroll
  for (int nt = 0; nt < 4; ++nt) {
    const int c = (n0 + wn * 64 + nt * 16 + fr) & 1023;
    const int h = c >> 6, d = c & 63;
    const float bs = bp[c];
#pragma unroll
    for (int mt = 0; mt < 8; ++mt) {
      const int mbase = m0 + wm * 128 + mt * 16 + quad * 4;
      const int b = mbase >> 11, s0 = mbase & 2047;
      if (seg < 2) {
        unsigned short* dst = QK + (((size_t)(b * NH + h)) * SEQ + s0) * HD + d;
#pragma unroll
        for (int r = 0; r < 4; ++r)
          dst[(size_t)r * HD] = (unsigned short)f2bf((acc[mt][nt][r] + bs) * scale);
      } else {  // V^T: rows contiguous in s -> 8B store
        uint2 pk;
        pk.x = pk2bf(acc[mt][nt][0] + bs, acc[mt][nt][1] + bs);
        pk.y = pk2bf(acc[mt][nt][2] + bs, acc[mt][nt][3] + bs);
        *reinterpret_cast<uint2*>(
            Vto + (((size_t)(b * NH + h)) * HD + d) * SEQ + s0) = pk;
      }
    }
  }
#undef G8_STAGE_A
#undef G8_STAGE_B
#undef G8_READ
#undef G8_MMA
#undef G8_BAR
#undef G8_VM2
}

// TM x 128-tile GEMM, BK=64, global_load_lds staging, XOR-swizzled LDS chunks.
// Double-buffered LDS, ONE barrier per K-step. Used for the out projection
// (MODE 1: fp32 C[M][1024] + bias0).
template <int MODE, int TM>
__global__ __launch_bounds__(256) void gemm128(
    const unsigned short* __restrict__ A, const unsigned short* __restrict__ B,
    const float* __restrict__ bias0, const float* __restrict__ bias1,
    const float* __restrict__ bias2, float* __restrict__ Cf,
    unsigned short* __restrict__ Qo, unsigned short* __restrict__ Ko,
    unsigned short* __restrict__ Vto, int Kdim) {
  constexpr int MT = TM / 32;  // acc rows (16-row frags) per wave
  __shared__ __align__(16) unsigned short As[2][TM * 64];
  __shared__ __align__(16) unsigned short Bs[2][128 * 64];
  const int tid = threadIdx.x;
  const int wave = tid >> 6, lane = tid & 63;
  const int wm = wave >> 1, wn = wave & 1;  // 2x2 waves
  const int fr = lane & 15, quad = lane >> 4;
  const int fx = fr & 7;  // swizzle key for fragment reads
  const int n0 = blockIdx.x * 128, m0 = blockIdx.y * TM;

  const int srowg = lane >> 3;
  const int schunk = (lane & 7) ^ (srowg & 7);
  const unsigned short* Abase =
      A + (size_t)(m0 + wave * (TM / 4) + srowg) * Kdim + schunk * 8;
  const unsigned short* Bbase =
      B + (size_t)(n0 + wave * 32 + srowg) * Kdim + schunk * 8;
  const int awoff = (wave * (TM / 4)) * 64;
  const int bwoff = (wave * 32) * 64;

  f32x4 acc[MT][4];
#pragma unroll
  for (int mt = 0; mt < MT; ++mt)
#pragma unroll
    for (int nt = 0; nt < 4; ++nt) acc[mt][nt] = f32x4{0.f, 0.f, 0.f, 0.f};

  // prologue: stage K-tile 0 into buffer 0
#pragma unroll
  for (int t = 0; t < TM / 32; ++t)
    gl2lds16(Abase + (size_t)(t * 8) * Kdim, As[0] + awoff + t * 8 * 64);
#pragma unroll
  for (int t = 0; t < 4; ++t)
    gl2lds16(Bbase + (size_t)(t * 8) * Kdim, Bs[0] + bwoff + t * 8 * 64);

  const int nk = Kdim >> 6;
  for (int kk = 0; kk < nk; ++kk) {
    __syncthreads();   // drains DMA[kk] (vmcnt) + guards buffer reuse
    if (kk + 1 < nk) { // prefetch next K-tile into the other buffer
      const int k0n = (kk + 1) * 64;
      unsigned short* An = As[(kk + 1) & 1] + awoff;
      unsigned short* Bn = Bs[(kk + 1) & 1] + bwoff;
#pragma unroll
      for (int t = 0; t < TM / 32; ++t)
        gl2lds16(Abase + (size_t)(t * 8) * Kdim + k0n, An + t * 8 * 64);
#pragma unroll
      for (int t = 0; t < 4; ++t)
        gl2lds16(Bbase + (size_t)(t * 8) * Kdim + k0n, Bn + t * 8 * 64);
    }
    const unsigned short* Acur = As[kk & 1];
    const unsigned short* Bcur = Bs[kk & 1];
#pragma unroll
    for (int ks = 0; ks < 2; ++ks) {
      bf16x8 af[MT], bfv[4];
#pragma unroll
      for (int mt = 0; mt < MT; ++mt)
        af[mt] = *reinterpret_cast<const bf16x8*>(
            Acur + (wm * (TM / 2) + mt * 16 + fr) * 64 + ((ks * 4 + quad) ^ fx) * 8);
#pragma unroll
      for (int nt = 0; nt < 4; ++nt)
        bfv[nt] = *reinterpret_cast<const bf16x8*>(
            Bcur + (wn * 64 + nt * 16 + fr) * 64 + ((ks * 4 + quad) ^ fx) * 8);
#pragma unroll
      for (int mt = 0; mt < MT; ++mt)
#pragma unroll
        for (int nt = 0; nt < 4; ++nt)
          acc[mt][nt] = __builtin_amdgcn_mfma_f32_16x16x32_bf16(
              af[mt], bfv[nt], acc[mt][nt], 0, 0, 0);
    }
  }

  if (MODE == 0) {
    const int seg = n0 >> 10;
    const float* bp = (seg == 0) ? bias0 : (seg == 1) ? bias1 : bias2;
    const float scale = (seg == 0) ? 0.1803368809f : 1.0f;
    unsigned short* QK = (seg == 0) ? Qo : Ko;
#pragma unroll
    for (int nt = 0; nt < 4; ++nt) {
      const int c = (n0 + wn * 64 + nt * 16 + fr) & 1023;
      const int h = c >> 6, d = c & 63;
      const float bs = bp[c];
#pragma unroll
      for (int mt = 0; mt < MT; ++mt) {
        const int mbase = m0 + wm * (TM / 2) + mt * 16 + quad * 4;
        const int b = mbase >> 11, s0 = mbase & 2047;
        if (seg < 2) {
          unsigned short* dst = QK + (((size_t)(b * NH + h)) * SEQ + s0) * HD + d;
#pragma unroll
          for (int r = 0; r < 4; ++r)
            dst[(size_t)r * HD] = (unsigned short)f2bf((acc[mt][nt][r] + bs) * scale);
        } else {
          uint2 pk;
          pk.x = pk2bf(acc[mt][nt][0] + bs, acc[mt][nt][1] + bs);
          pk.y = pk2bf(acc[mt][nt][2] + bs, acc[mt][nt][3] + bs);
          *reinterpret_cast<uint2*>(
              Vto + (((size_t)(b * NH + h)) * HD + d) * SEQ + s0) = pk;
        }
      }
    }
  } else {
#pragma unroll
    for (int nt = 0; nt < 4; ++nt) {
      const int cg = n0 + wn * 64 + nt * 16 + fr;
      const float bs = bias0[cg];
#pragma unroll
      for (int mt = 0; mt < MT; ++mt) {
        const int mbase = m0 + wm * (TM / 2) + mt * 16 + quad * 4;
#pragma unroll
        for (int r = 0; r < 4; ++r)
          Cf[(size_t)(mbase + r) * DMODEL + cg] = acc[mt][nt][r] + bs;
      }
    }
  }
}

// MFMA flash attention, exp2 domain (round-4 proven version: 48.6-49.2 us).
// Single 64-row i-tile per block, grid 1024, 4 blocks/CU (LDS 32768 B).
// pi-permuted K rows -> P never touches LDS; stale-max softmax off the
// critical path; defer-8 rescale post-PV.
__global__ __launch_bounds__(256, 4) void attn_mfma_kernel(
    const unsigned short* __restrict__ Qg, const unsigned short* __restrict__ Kg,
    const unsigned short* __restrict__ Vtg, const int* __restrict__ mask,
    unsigned short* __restrict__ concat) {
  const int w = blockIdx.x >> 8;        // phase 0..3
  const int c = blockIdx.x & 255;
  const int gg = c >> 5;                // 0..7
  const int bh = c & 31;
  const int ib = (w == 0) ? (31 - gg) : (w == 1) ? gg : (w == 2) ? (23 - gg) : (8 + gg);
  const int b = bh >> 4, h = bh & 15;
  const int tid = threadIdx.x;
  const int wave = tid >> 6, lane = tid & 63;
  const int quad = lane >> 4, fr = lane & 15;
  const int fx = fr & 7;

  __shared__ __align__(16) unsigned short Ks[2][64 * 64];   // swizzled, pi-permuted rows
  __shared__ __align__(16) unsigned short Vts[2][64 * 64];  // swizzled, pitch 64

  const unsigned short* Qb = Qg + ((size_t)bh * SEQ) * HD;
  const unsigned short* Kb = Kg + ((size_t)bh * SEQ) * HD;
  const unsigned short* Vtb = Vtg + ((size_t)bh * HD) * SEQ;
  const int* maskb = mask + b * SEQ;

  bool badl = false;
  {
    const int4* mp4 = reinterpret_cast<const int4*>(maskb);
#pragma unroll
    for (int u = 0; u < 8; ++u) {
      int4 v = mp4[lane * 8 + u];
      badl |= !(v.x && v.y && v.z && v.w);
    }
  }
  const unsigned long long bm = __ballot(badl);

  const int ir = ib * 64 + wave * 16 + fr;  // this lane's Q row (softmax owner)
  const bf16x8 q0 = *reinterpret_cast<const bf16x8*>(Qb + (size_t)ir * HD + quad * 8);
  const bf16x8 q1 = *reinterpret_cast<const bf16x8*>(Qb + (size_t)ir * HD + quad * 8 + 32);
  const int padi = maskb[ir];

  f32x4 o[4];
#pragma unroll
  for (int vt = 0; vt < 4; ++vt) o[vt] = f32x4{0.f, 0.f, 0.f, 0.f};
  float mr = -1e20f;
  float lq = 0.f;

  const int srow8 = lane >> 3;
  const int sch8 = (lane & 7) ^ (srow8 & 7);
  const int kprow = (wave >> 1) * 32 + ((srow8 >> 2)) * 8 + (wave & 1) * 4 + (srow8 & 3);
  const unsigned short* Kcol = Kb + sch8 * 8;
  const unsigned short* Vsrc = Vtb + (size_t)(wave * 16 + srow8) * SEQ + sch8 * 8;
  const int cA0 = (quad ^ fx) * 8;
  const int cA1 = ((quad + 4) ^ fx) * 8;

  {
    unsigned short* KsW = Ks[0] + (wave * 16) * 64;
    unsigned short* VtsW = Vts[0] + (wave * 16) * 64;
#pragma unroll
    for (int t = 0; t < 2; ++t) {
      gl2lds16(Kcol + (size_t)(kprow + t * 16) * HD, KsW + t * 8 * 64);
      gl2lds16(Vsrc + (size_t)(t * 8) * SEQ, VtsW + t * 8 * 64);
    }
  }

  for (int jc = 0; jc <= ib; ++jc) {
    __syncthreads();
    if (jc < ib) {
      const int jn = (jc + 1) * 64;
      unsigned short* KsW = Ks[(jc + 1) & 1] + (wave * 16) * 64;
      unsigned short* VtsW = Vts[(jc + 1) & 1] + (wave * 16) * 64;
#pragma unroll
      for (int t = 0; t < 2; ++t) {
        gl2lds16(Kcol + (size_t)(jn + kprow + t * 16) * HD, KsW + t * 8 * 64);
        gl2lds16(Vsrc + (size_t)(t * 8) * SEQ + jn, VtsW + t * 8 * 64);
      }
    }
    const unsigned short* Kcur = Ks[jc & 1];
    const unsigned short* Vcur = Vts[jc & 1];
    const int j0 = jc * 64;
    const bool tb = ((bm >> (2 * jc)) & 3ull) != 0ull;

    f32x4 st[4];
    __builtin_amdgcn_s_setprio(1);
#pragma unroll
    for (int jt = 0; jt < 4; ++jt) {
      bf16x8 ka0 = *reinterpret_cast<const bf16x8*>(&Kcur[(jt * 16 + fr) * 64 + cA0]);
      bf16x8 ka1 = *reinterpret_cast<const bf16x8*>(&Kcur[(jt * 16 + fr) * 64 + cA1]);
      st[jt] = f32x4{0.f, 0.f, 0.f, 0.f};
      st[jt] = __builtin_amdgcn_mfma_f32_16x16x32_bf16(ka0, q0, st[jt], 0, 0, 0);
      st[jt] = __builtin_amdgcn_mfma_f32_16x16x32_bf16(ka1, q1, st[jt], 0, 0, 0);
    }
    __builtin_amdgcn_s_setprio(0);

    if (tb) {
      const int4* mp = reinterpret_cast<const int4*>(maskb + j0);
#pragma unroll
      for (int jt = 0; jt < 4; ++jt) {
        const int4 mv = mp[(jt >> 1) * 8 + quad * 2 + (jt & 1)];
        if (mv.x == 0) st[jt][0] = -1e30f;
        if (mv.y == 0) st[jt][1] = -1e30f;
        if (mv.z == 0) st[jt][2] = -1e30f;
        if (mv.w == 0) st[jt][3] = -1e30f;
      }
    }
    if (jc == ib) {
#pragma unroll
      for (int jt = 0; jt < 4; ++jt) {
        const int jb = j0 + (jt >> 1) * 32 + quad * 8 + (jt & 1) * 4;
#pragma unroll
        for (int r = 0; r < 4; ++r)
          if (jb + r > ir) st[jt][r] = -1e30f;
      }
    }

    float tmax = -1e30f;
#pragma unroll
    for (int jt = 0; jt < 4; ++jt)
#pragma unroll
      for (int r = 0; r < 4; ++r) tmax = fmaxf(tmax, st[jt][r]);
    tmax = fmaxf(tmax, __shfl_xor(tmax, 16));
    {
      uix2 rr = __builtin_amdgcn_permlane32_swap(__float_as_uint(tmax),
                                                 __float_as_uint(tmax), false, false);
      tmax = fmaxf(__uint_as_float(rr.x), __uint_as_float(rr.y));
    }
    if (jc == 0) mr = fmaxf(tmax, -1e20f);

    unsigned int pw[8];
#pragma unroll
    for (int jt = 0; jt < 4; ++jt) {
      float p0 = __builtin_amdgcn_exp2f(fminf(st[jt][0] - mr, 60.f));
      float p1 = __builtin_amdgcn_exp2f(fminf(st[jt][1] - mr, 60.f));
      float p2 = __builtin_amdgcn_exp2f(fminf(st[jt][2] - mr, 60.f));
      float p3 = __builtin_amdgcn_exp2f(fminf(st[jt][3] - mr, 60.f));
      lq += (p0 + p1) + (p2 + p3);
      pw[2 * jt] = pk2bf(p0, p1);
      pw[2 * jt + 1] = pk2bf(p2, p3);
    }
    const bf16x8 pa0 = __builtin_bit_cast(bf16x8, uix4{pw[0], pw[1], pw[2], pw[3]});
    const bf16x8 pa1 = __builtin_bit_cast(bf16x8, uix4{pw[4], pw[5], pw[6], pw[7]});

    __builtin_amdgcn_s_setprio(1);
#pragma unroll
    for (int vt = 0; vt < 4; ++vt) {
      bf16x8 vb0 = *reinterpret_cast<const bf16x8*>(&Vcur[(vt * 16 + fr) * 64 + cA0]);
      bf16x8 vb1 = *reinterpret_cast<const bf16x8*>(&Vcur[(vt * 16 + fr) * 64 + cA1]);
      o[vt] = __builtin_amdgcn_mfma_f32_16x16x32_bf16(vb0, pa0, o[vt], 0, 0, 0);
      o[vt] = __builtin_amdgcn_mfma_f32_16x16x32_bf16(vb1, pa1, o[vt], 0, 0, 0);
    }
    __builtin_amdgcn_s_setprio(0);

    if (jc > 0) {
      const bool upd = __ballot(tmax > mr + 8.f) != 0ull;
      if (upd) {
        const float mn = fmaxf(mr, tmax);
        const float corr = __builtin_amdgcn_exp2f(mr - mn);
        mr = mn;
        lq *= corr;
#pragma unroll
        for (int vt = 0; vt < 4; ++vt) {
          o[vt][0] *= corr; o[vt][1] *= corr; o[vt][2] *= corr; o[vt][3] *= corr;
        }
      }
    }
  }

  float lr = lq;
  lr += __shfl_xor(lr, 16);
  lr += __shfl_xor(lr, 32);
  const float inv = (padi != 0 && lr > 0.f) ? 1.f / lr : 0.f;
  unsigned short* orow = concat + ((size_t)(b * SEQ + ir)) * DMODEL + h * HD;
#pragma unroll
  for (int vt = 0; vt < 4; ++vt) {
    uint2 pk;
    pk.x = pk2bf(o[vt][0] * inv, o[vt][1] * inv);
    pk.y = pk2bf(o[vt][2] * inv, o[vt][3] * inv);
    *reinterpret_cast<uint2*>(orow + vt * 16 + quad * 4) = pk;
  }
}

extern "C" void kernel_launch(void* const* d_in, const int* in_sizes, int n_in,
                              void* d_out, int out_size, void* d_ws, size_t ws_size,
                              hipStream_t stream) {
  (void)in_sizes; (void)n_in; (void)out_size;
  const float* x  = (const float*)d_in[0];
  const int* mask = (const int*)d_in[1];
  const float* Wq = (const float*)d_in[2];
  const float* bq = (const float*)d_in[3];
  const float* Wk = (const float*)d_in[4];
  const float* bk = (const float*)d_in[5];
  const float* Wv = (const float*)d_in[6];
  const float* bv = (const float*)d_in[7];
  const float* Wo = (const float*)d_in[8];
  const float* bo = (const float*)d_in[9];
  float* out = (float*)d_out;

  char* ws = (char*)d_ws;
  if (ws_size < (48ull << 20)) return;
  unsigned short* xb  = (unsigned short*)(ws);                 // 8 MB x bf16 [4096][1024]
  unsigned short* wqb = (unsigned short*)(ws + (8ull  << 20)); // wq|wk|wv contiguous ->
  unsigned short* wkb = (unsigned short*)(ws + (10ull << 20)); //   [3072][1024] B matrix
  unsigned short* wvb = (unsigned short*)(ws + (12ull << 20));
  unsigned short* wob = (unsigned short*)(ws + (14ull << 20));
  unsigned short* Qb  = (unsigned short*)(ws + (16ull << 20)); // 8 MB [b,h,s,64] (xscale)
  unsigned short* Kb  = (unsigned short*)(ws + (24ull << 20)); // 8 MB [b,h,s,64]
  unsigned short* Vtb = (unsigned short*)(ws + (32ull << 20)); // 8 MB [b,h,64,s]
  unsigned short* cb  = (unsigned short*)(ws + (40ull << 20)); // 8 MB concat bf16

  cast_all_kernel<<<4096, 256, 0, stream>>>(x, Wq, Wk, Wv, Wo, xb, wqb, wkb, wvb, wob);

  // fused QKV projection, 8-phase 256^2: B = [wq; wk; wv] = [3072][1024]
  gemm8ph_qkv<<<dim3(12, 16), 512, 0, stream>>>(xb, wqb, bq, bk, bv, Qb, Kb, Vtb);

  attn_mfma_kernel<<<1024, 256, 0, stream>>>(Qb, Kb, Vtb, mask, cb);

  // out projection: 64-row M-tiles -> 512 blocks (2/CU)
  gemm128<1, 64><<<dim3(8, 64), 256, 0, stream>>>(cb, wob, bo, nullptr, nullptr,
                                                  out, nullptr, nullptr, nullptr, 1024);
}

// Round 7
// 194.887 us; speedup vs baseline: 1.0505x; 1.0146x over previous
//
#include <hip/hip_runtime.h>

#define SEQ 2048
#define NH 16
#define HD 64
#define DMODEL 1024

__device__ __forceinline__ unsigned int f2bf(float f) {
  // fp32 -> bf16 bits, round-to-nearest-even (finite inputs only)
  unsigned int u = __float_as_uint(f);
  return ((u + 0x7fffu + ((u >> 16) & 1u)) >> 16) & 0xffffu;
}

// packed fp32x2 -> bf16x2 (RNE via __bf16 cvt)
__device__ __forceinline__ unsigned int pk2bf(float a, float b) {
  unsigned short ua = __builtin_bit_cast(unsigned short, (__bf16)a);
  unsigned short ub = __builtin_bit_cast(unsigned short, (__bf16)b);
  return (unsigned int)ua | ((unsigned int)ub << 16);
}

typedef __bf16 bf16x8 __attribute__((ext_vector_type(8)));
typedef float f32x4 __attribute__((ext_vector_type(4)));
typedef unsigned int uix4 __attribute__((ext_vector_type(4)));
typedef unsigned int uix2 __attribute__((ext_vector_type(2)));

// async global->LDS, 16B per lane; LDS dest = wave-uniform base + lane*16
__device__ __forceinline__ void gl2lds16(const unsigned short* g, unsigned short* l) {
  __builtin_amdgcn_global_load_lds(
      (const __attribute__((address_space(1))) unsigned int*)g,
      (__attribute__((address_space(3))) unsigned int*)l, 16, 0, 0);
}

// one launch casts x + all four weight matrices to bf16
__global__ __launch_bounds__(256) void cast_all_kernel(
    const float* __restrict__ x, const float* __restrict__ wq,
    const float* __restrict__ wk, const float* __restrict__ wv,
    const float* __restrict__ wo,
    unsigned short* __restrict__ xb, unsigned short* __restrict__ wqb,
    unsigned short* __restrict__ wkb, unsigned short* __restrict__ wvb,
    unsigned short* __restrict__ wob) {
  int idx = blockIdx.x * 256 + threadIdx.x;
  if (idx >= 1048576) return;
  const float* src;
  unsigned short* dst;
  int off;
  if (idx < 524288) {
    src = x; dst = xb; off = idx;
  } else {
    int t = idx - 524288;
    int w = t >> 17;
    off = t & 131071;
    src = (w == 0) ? wq : (w == 1) ? wk : (w == 2) ? wv : wo;
    dst = (w == 0) ? wqb : (w == 1) ? wkb : (w == 2) ? wvb : wob;
  }
  const float4* p = reinterpret_cast<const float4*>(src) + (size_t)off * 2;
  float4 a = p[0], b = p[1];
  uint4 o;
  o.x = f2bf(a.x) | (f2bf(a.y) << 16);
  o.y = f2bf(a.z) | (f2bf(a.w) << 16);
  o.z = f2bf(b.x) | (f2bf(b.y) << 16);
  o.w = f2bf(b.z) | (f2bf(b.w) << 16);
  reinterpret_cast<uint4*>(dst)[off] = o;
}

// TM x 128-tile GEMM, BK=64, global_load_lds staging, XOR-swizzled LDS chunks.
// Double-buffered LDS, ONE barrier per K-step (round-4 proven; 8-phase 256^2
// regressed: grid underfill 192<256 CUs + 1 block/CU -> reverted, ERRATA r6).
// ROUND 7: T1 XCD-aware block swizzle. Dispatch round-robins flat block ids
// across the 8 XCDs; remapping flat -> (flat&7)*(nwg/8) + flat>>3 gives each
// XCD a CONTIGUOUS chunk of tiles -> A/B panel re-reads become same-XCD L2
// hits (gemm0 measured 41.5 MB FETCH vs ~14 MB compulsory without it).
// Both grids are %8==0 (768, 512) so the simple bijective form is valid.
// MODE 0: fused QKV epilogue (cols 0..1023 Q *qscale, 1024..2047 K, 2048..3071 V^T).
// MODE 1: fp32 C[M][1024] + bias0 (out projection).
template <int MODE, int TM>
__global__ __launch_bounds__(256) void gemm128(
    const unsigned short* __restrict__ A, const unsigned short* __restrict__ B,
    const float* __restrict__ bias0, const float* __restrict__ bias1,
    const float* __restrict__ bias2, float* __restrict__ Cf,
    unsigned short* __restrict__ Qo, unsigned short* __restrict__ Ko,
    unsigned short* __restrict__ Vto, int Kdim) {
  constexpr int MT = TM / 32;  // acc rows (16-row frags) per wave
  __shared__ __align__(16) unsigned short As[2][TM * 64];
  __shared__ __align__(16) unsigned short Bs[2][128 * 64];
  const int tid = threadIdx.x;
  const int wave = tid >> 6, lane = tid & 63;
  const int wm = wave >> 1, wn = wave & 1;  // 2x2 waves
  const int fr = lane & 15, quad = lane >> 4;
  const int fx = fr & 7;  // swizzle key for fragment reads

  // T1: XCD-contiguous tile remap (requires nwg % 8 == 0 -- both launches are)
  const int gx = gridDim.x;
  const int flat = blockIdx.y * gx + blockIdx.x;
  const int cpx = (gx * gridDim.y) >> 3;
  const int swz = (flat & 7) * cpx + (flat >> 3);
  const int n0 = (swz % gx) * 128, m0 = (swz / gx) * TM;

  // staging: lane -> (row = lane>>3, swizzled chunk = (lane&7) ^ ((lane>>3)&7))
  const int srowg = lane >> 3;
  const int schunk = (lane & 7) ^ (srowg & 7);
  const unsigned short* Abase =
      A + (size_t)(m0 + wave * (TM / 4) + srowg) * Kdim + schunk * 8;
  const unsigned short* Bbase =
      B + (size_t)(n0 + wave * 32 + srowg) * Kdim + schunk * 8;
  const int awoff = (wave * (TM / 4)) * 64;
  const int bwoff = (wave * 32) * 64;

  f32x4 acc[MT][4];
#pragma unroll
  for (int mt = 0; mt < MT; ++mt)
#pragma unroll
    for (int nt = 0; nt < 4; ++nt) acc[mt][nt] = f32x4{0.f, 0.f, 0.f, 0.f};

  // prologue: stage K-tile 0 into buffer 0
#pragma unroll
  for (int t = 0; t < TM / 32; ++t)
    gl2lds16(Abase + (size_t)(t * 8) * Kdim, As[0] + awoff + t * 8 * 64);
#pragma unroll
  for (int t = 0; t < 4; ++t)
    gl2lds16(Bbase + (size_t)(t * 8) * Kdim, Bs[0] + bwoff + t * 8 * 64);

  const int nk = Kdim >> 6;
  for (int kk = 0; kk < nk; ++kk) {
    __syncthreads();   // drains DMA[kk] (vmcnt) + guards buffer reuse
    if (kk + 1 < nk) { // prefetch next K-tile into the other buffer
      const int k0n = (kk + 1) * 64;
      unsigned short* An = As[(kk + 1) & 1] + awoff;
      unsigned short* Bn = Bs[(kk + 1) & 1] + bwoff;
#pragma unroll
      for (int t = 0; t < TM / 32; ++t)
        gl2lds16(Abase + (size_t)(t * 8) * Kdim + k0n, An + t * 8 * 64);
#pragma unroll
      for (int t = 0; t < 4; ++t)
        gl2lds16(Bbase + (size_t)(t * 8) * Kdim + k0n, Bn + t * 8 * 64);
    }
    const unsigned short* Acur = As[kk & 1];
    const unsigned short* Bcur = Bs[kk & 1];
#pragma unroll
    for (int ks = 0; ks < 2; ++ks) {
      bf16x8 af[MT], bfv[4];
#pragma unroll
      for (int mt = 0; mt < MT; ++mt)
        af[mt] = *reinterpret_cast<const bf16x8*>(
            Acur + (wm * (TM / 2) + mt * 16 + fr) * 64 + ((ks * 4 + quad) ^ fx) * 8);
#pragma unroll
      for (int nt = 0; nt < 4; ++nt)
        bfv[nt] = *reinterpret_cast<const bf16x8*>(
            Bcur + (wn * 64 + nt * 16 + fr) * 64 + ((ks * 4 + quad) ^ fx) * 8);
#pragma unroll
      for (int mt = 0; mt < MT; ++mt)
#pragma unroll
        for (int nt = 0; nt < 4; ++nt)
          acc[mt][nt] = __builtin_amdgcn_mfma_f32_16x16x32_bf16(
              af[mt], bfv[nt], acc[mt][nt], 0, 0, 0);
    }
  }

  // epilogue. C/D: col = lane&15, row = quad*4+reg (m89/m91-verified).
  if (MODE == 0) {
    const int seg = n0 >> 10;  // uniform per block
    const float* bp = (seg == 0) ? bias0 : (seg == 1) ? bias1 : bias2;
    // Q pre-scaled by (1/sqrt(64)) * log2(e): attention works in exp2 domain
    const float scale = (seg == 0) ? 0.1803368809f : 1.0f;
    unsigned short* QK = (seg == 0) ? Qo : Ko;
#pragma unroll
    for (int nt = 0; nt < 4; ++nt) {
      const int c = (n0 + wn * 64 + nt * 16 + fr) & 1023;
      const int h = c >> 6, d = c & 63;
      const float bs = bp[c];
#pragma unroll
      for (int mt = 0; mt < MT; ++mt) {
        const int mbase = m0 + wm * (TM / 2) + mt * 16 + quad * 4;
        const int b = mbase >> 11, s0 = mbase & 2047;
        if (seg < 2) {
          unsigned short* dst = QK + (((size_t)(b * NH + h)) * SEQ + s0) * HD + d;
#pragma unroll
          for (int r = 0; r < 4; ++r)
            dst[(size_t)r * HD] = (unsigned short)f2bf((acc[mt][nt][r] + bs) * scale);
        } else {  // V^T: rows contiguous in s -> 8B store
          uint2 pk;
          pk.x = pk2bf(acc[mt][nt][0] + bs, acc[mt][nt][1] + bs);
          pk.y = pk2bf(acc[mt][nt][2] + bs, acc[mt][nt][3] + bs);
          *reinterpret_cast<uint2*>(
              Vto + (((size_t)(b * NH + h)) * HD + d) * SEQ + s0) = pk;
        }
      }
    }
  } else {
#pragma unroll
    for (int nt = 0; nt < 4; ++nt) {
      const int cg = n0 + wn * 64 + nt * 16 + fr;
      const float bs = bias0[cg];
#pragma unroll
      for (int mt = 0; mt < MT; ++mt) {
        const int mbase = m0 + wm * (TM / 2) + mt * 16 + quad * 4;
#pragma unroll
        for (int r = 0; r < 4; ++r)
          Cf[(size_t)(mbase + r) * DMODEL + cg] = acc[mt][nt][r] + bs;
      }
    }
  }
}

// MFMA flash attention, exp2 domain (round-4 proven version: 48.6-49.2 us).
// Single 64-row i-tile per block, grid 1024, 4 blocks/CU (LDS 32768 B).
// pi-permuted K rows -> P never touches LDS; stale-max softmax off the
// critical path; defer-8 rescale post-PV.
__global__ __launch_bounds__(256, 4) void attn_mfma_kernel(
    const unsigned short* __restrict__ Qg, const unsigned short* __restrict__ Kg,
    const unsigned short* __restrict__ Vtg, const int* __restrict__ mask,
    unsigned short* __restrict__ concat) {
  const int w = blockIdx.x >> 8;        // phase 0..3
  const int c = blockIdx.x & 255;
  const int gg = c >> 5;                // 0..7
  const int bh = c & 31;
  const int ib = (w == 0) ? (31 - gg) : (w == 1) ? gg : (w == 2) ? (23 - gg) : (8 + gg);
  const int b = bh >> 4, h = bh & 15;
  const int tid = threadIdx.x;
  const int wave = tid >> 6, lane = tid & 63;
  const int quad = lane >> 4, fr = lane & 15;
  const int fx = fr & 7;

  __shared__ __align__(16) unsigned short Ks[2][64 * 64];   // swizzled, pi-permuted rows
  __shared__ __align__(16) unsigned short Vts[2][64 * 64];  // swizzled, pitch 64

  const unsigned short* Qb = Qg + ((size_t)bh * SEQ) * HD;
  const unsigned short* Kb = Kg + ((size_t)bh * SEQ) * HD;
  const unsigned short* Vtb = Vtg + ((size_t)bh * HD) * SEQ;
  const int* maskb = mask + b * SEQ;

  bool badl = false;
  {
    const int4* mp4 = reinterpret_cast<const int4*>(maskb);
#pragma unroll
    for (int u = 0; u < 8; ++u) {
      int4 v = mp4[lane * 8 + u];
      badl |= !(v.x && v.y && v.z && v.w);
    }
  }
  const unsigned long long bm = __ballot(badl);

  const int ir = ib * 64 + wave * 16 + fr;  // this lane's Q row (softmax owner)
  const bf16x8 q0 = *reinterpret_cast<const bf16x8*>(Qb + (size_t)ir * HD + quad * 8);
  const bf16x8 q1 = *reinterpret_cast<const bf16x8*>(Qb + (size_t)ir * HD + quad * 8 + 32);
  const int padi = maskb[ir];

  f32x4 o[4];
#pragma unroll
  for (int vt = 0; vt < 4; ++vt) o[vt] = f32x4{0.f, 0.f, 0.f, 0.f};
  float mr = -1e20f;
  float lq = 0.f;

  const int srow8 = lane >> 3;
  const int sch8 = (lane & 7) ^ (srow8 & 7);
  const int kprow = (wave >> 1) * 32 + ((srow8 >> 2)) * 8 + (wave & 1) * 4 + (srow8 & 3);
  const unsigned short* Kcol = Kb + sch8 * 8;
  const unsigned short* Vsrc = Vtb + (size_t)(wave * 16 + srow8) * SEQ + sch8 * 8;
  const int cA0 = (quad ^ fx) * 8;
  const int cA1 = ((quad + 4) ^ fx) * 8;

  {
    unsigned short* KsW = Ks[0] + (wave * 16) * 64;
    unsigned short* VtsW = Vts[0] + (wave * 16) * 64;
#pragma unroll
    for (int t = 0; t < 2; ++t) {
      gl2lds16(Kcol + (size_t)(kprow + t * 16) * HD, KsW + t * 8 * 64);
      gl2lds16(Vsrc + (size_t)(t * 8) * SEQ, VtsW + t * 8 * 64);
    }
  }

  for (int jc = 0; jc <= ib; ++jc) {
    __syncthreads();
    if (jc < ib) {
      const int jn = (jc + 1) * 64;
      unsigned short* KsW = Ks[(jc + 1) & 1] + (wave * 16) * 64;
      unsigned short* VtsW = Vts[(jc + 1) & 1] + (wave * 16) * 64;
#pragma unroll
      for (int t = 0; t < 2; ++t) {
        gl2lds16(Kcol + (size_t)(jn + kprow + t * 16) * HD, KsW + t * 8 * 64);
        gl2lds16(Vsrc + (size_t)(t * 8) * SEQ + jn, VtsW + t * 8 * 64);
      }
    }
    const unsigned short* Kcur = Ks[jc & 1];
    const unsigned short* Vcur = Vts[jc & 1];
    const int j0 = jc * 64;
    const bool tb = ((bm >> (2 * jc)) & 3ull) != 0ull;

    f32x4 st[4];
    __builtin_amdgcn_s_setprio(1);
#pragma unroll
    for (int jt = 0; jt < 4; ++jt) {
      bf16x8 ka0 = *reinterpret_cast<const bf16x8*>(&Kcur[(jt * 16 + fr) * 64 + cA0]);
      bf16x8 ka1 = *reinterpret_cast<const bf16x8*>(&Kcur[(jt * 16 + fr) * 64 + cA1]);
      st[jt] = f32x4{0.f, 0.f, 0.f, 0.f};
      st[jt] = __builtin_amdgcn_mfma_f32_16x16x32_bf16(ka0, q0, st[jt], 0, 0, 0);
      st[jt] = __builtin_amdgcn_mfma_f32_16x16x32_bf16(ka1, q1, st[jt], 0, 0, 0);
    }
    __builtin_amdgcn_s_setprio(0);

    if (tb) {
      const int4* mp = reinterpret_cast<const int4*>(maskb + j0);
#pragma unroll
      for (int jt = 0; jt < 4; ++jt) {
        const int4 mv = mp[(jt >> 1) * 8 + quad * 2 + (jt & 1)];
        if (mv.x == 0) st[jt][0] = -1e30f;
        if (mv.y == 0) st[jt][1] = -1e30f;
        if (mv.z == 0) st[jt][2] = -1e30f;
        if (mv.w == 0) st[jt][3] = -1e30f;
      }
    }
    if (jc == ib) {
#pragma unroll
      for (int jt = 0; jt < 4; ++jt) {
        const int jb = j0 + (jt >> 1) * 32 + quad * 8 + (jt & 1) * 4;
#pragma unroll
        for (int r = 0; r < 4; ++r)
          if (jb + r > ir) st[jt][r] = -1e30f;
      }
    }

    float tmax = -1e30f;
#pragma unroll
    for (int jt = 0; jt < 4; ++jt)
#pragma unroll
      for (int r = 0; r < 4; ++r) tmax = fmaxf(tmax, st[jt][r]);
    tmax = fmaxf(tmax, __shfl_xor(tmax, 16));
    {
      uix2 rr = __builtin_amdgcn_permlane32_swap(__float_as_uint(tmax),
                                                 __float_as_uint(tmax), false, false);
      tmax = fmaxf(__uint_as_float(rr.x), __uint_as_float(rr.y));
    }
    if (jc == 0) mr = fmaxf(tmax, -1e20f);

    unsigned int pw[8];
#pragma unroll
    for (int jt = 0; jt < 4; ++jt) {
      float p0 = __builtin_amdgcn_exp2f(fminf(st[jt][0] - mr, 60.f));
      float p1 = __builtin_amdgcn_exp2f(fminf(st[jt][1] - mr, 60.f));
      float p2 = __builtin_amdgcn_exp2f(fminf(st[jt][2] - mr, 60.f));
      float p3 = __builtin_amdgcn_exp2f(fminf(st[jt][3] - mr, 60.f));
      lq += (p0 + p1) + (p2 + p3);
      pw[2 * jt] = pk2bf(p0, p1);
      pw[2 * jt + 1] = pk2bf(p2, p3);
    }
    const bf16x8 pa0 = __builtin_bit_cast(bf16x8, uix4{pw[0], pw[1], pw[2], pw[3]});
    const bf16x8 pa1 = __builtin_bit_cast(bf16x8, uix4{pw[4], pw[5], pw[6], pw[7]});

    __builtin_amdgcn_s_setprio(1);
#pragma unroll
    for (int vt = 0; vt < 4; ++vt) {
      bf16x8 vb0 = *reinterpret_cast<const bf16x8*>(&Vcur[(vt * 16 + fr) * 64 + cA0]);
      bf16x8 vb1 = *reinterpret_cast<const bf16x8*>(&Vcur[(vt * 16 + fr) * 64 + cA1]);
      o[vt] = __builtin_amdgcn_mfma_f32_16x16x32_bf16(vb0, pa0, o[vt], 0, 0, 0);
      o[vt] = __builtin_amdgcn_mfma_f32_16x16x32_bf16(vb1, pa1, o[vt], 0, 0, 0);
    }
    __builtin_amdgcn_s_setprio(0);

    if (jc > 0) {
      const bool upd = __ballot(tmax > mr + 8.f) != 0ull;
      if (upd) {
        const float mn = fmaxf(mr, tmax);
        const float corr = __builtin_amdgcn_exp2f(mr - mn);
        mr = mn;
        lq *= corr;
#pragma unroll
        for (int vt = 0; vt < 4; ++vt) {
          o[vt][0] *= corr; o[vt][1] *= corr; o[vt][2] *= corr; o[vt][3] *= corr;
        }
      }
    }
  }

  float lr = lq;
  lr += __shfl_xor(lr, 16);
  lr += __shfl_xor(lr, 32);
  const float inv = (padi != 0 && lr > 0.f) ? 1.f / lr : 0.f;
  unsigned short* orow = concat + ((size_t)(b * SEQ + ir)) * DMODEL + h * HD;
#pragma unroll
  for (int vt = 0; vt < 4; ++vt) {
    uint2 pk;
    pk.x = pk2bf(o[vt][0] * inv, o[vt][1] * inv);
    pk.y = pk2bf(o[vt][2] * inv, o[vt][3] * inv);
    *reinterpret_cast<uint2*>(orow + vt * 16 + quad * 4) = pk;
  }
}

extern "C" void kernel_launch(void* const* d_in, const int* in_sizes, int n_in,
                              void* d_out, int out_size, void* d_ws, size_t ws_size,
                              hipStream_t stream) {
  (void)in_sizes; (void)n_in; (void)out_size;
  const float* x  = (const float*)d_in[0];
  const int* mask = (const int*)d_in[1];
  const float* Wq = (const float*)d_in[2];
  const float* bq = (const float*)d_in[3];
  const float* Wk = (const float*)d_in[4];
  const float* bk = (const float*)d_in[5];
  const float* Wv = (const float*)d_in[6];
  const float* bv = (const float*)d_in[7];
  const float* Wo = (const float*)d_in[8];
  const float* bo = (const float*)d_in[9];
  float* out = (float*)d_out;

  char* ws = (char*)d_ws;
  if (ws_size < (48ull << 20)) return;
  unsigned short* xb  = (unsigned short*)(ws);                 // 8 MB x bf16 [4096][1024]
  unsigned short* wqb = (unsigned short*)(ws + (8ull  << 20)); // wq|wk|wv contiguous ->
  unsigned short* wkb = (unsigned short*)(ws + (10ull << 20)); //   [3072][1024] B matrix
  unsigned short* wvb = (unsigned short*)(ws + (12ull << 20));
  unsigned short* wob = (unsigned short*)(ws + (14ull << 20));
  unsigned short* Qb  = (unsigned short*)(ws + (16ull << 20)); // 8 MB [b,h,s,64] (xscale)
  unsigned short* Kb  = (unsigned short*)(ws + (24ull << 20)); // 8 MB [b,h,s,64]
  unsigned short* Vtb = (unsigned short*)(ws + (32ull << 20)); // 8 MB [b,h,64,s]
  unsigned short* cb  = (unsigned short*)(ws + (40ull << 20)); // 8 MB concat bf16

  cast_all_kernel<<<4096, 256, 0, stream>>>(x, Wq, Wk, Wv, Wo, xb, wqb, wkb, wvb, wob);

  // fused QKV projection (2-phase dbuf 128^2, T1-swizzled): B = [wq;wk;wv]
  gemm128<0, 128><<<dim3(24, 32), 256, 0, stream>>>(xb, wqb, bq, bk, bv,
                                                    nullptr, Qb, Kb, Vtb, 1024);

  attn_mfma_kernel<<<1024, 256, 0, stream>>>(Qb, Kb, Vtb, mask, cb);

  // out projection: 64-row M-tiles -> 512 blocks (2/CU), T1-swizzled
  gemm128<1, 64><<<dim3(8, 64), 256, 0, stream>>>(cb, wob, bo, nullptr, nullptr,
                                                  out, nullptr, nullptr, nullptr, 1024);
}